// Round 1
// baseline (4331.830 us; speedup 1.0000x reference)
//
#include <hip/hip_runtime.h>

// Problem: x[16,32,32,32,32] fp32, w[32,64,3,3,3] fp32, b[64] fp32
// ConvTranspose3d(s=2,p=1,k=3) -> +bias,*0.5 -> maxpool2 (floor) -> mean -> clamp[0,1]
// out: [16,64] fp32 (1024 floats)
//
// Window w covers conv outputs {2w,2w+1} per dim, touching inputs {w,w+1} per dim.
// Per dim combos (delta = i-w, k, e = o-2w): (0,1,0) (0,2,1) (1,0,1). All in-bounds
// for w in [0,31), i in [0,32). No boundary handling needed anywhere.
//
// ws layout (floats): [0,1024): accumulator S[b][co]
//                     [1024, 1024+55296): wT[((co*8+cc)*27+k3)*4 + i] = w[cc*4+i][co][k3]

#define NWIN 29791  // 31^3

__global__ __launch_bounds__(256) void prep_kernel(const float* __restrict__ w,
                                                   float* __restrict__ ws) {
    int idx = blockIdx.x * 256 + threadIdx.x;
    if (idx < 1024) ws[idx] = 0.f;
    int t = idx - 1024;
    if (t >= 0 && t < 55296) {
        int i  = t & 3;
        int q  = t >> 2;          // [0,13824)
        int k3 = q % 27;
        int r  = q / 27;          // [0,512)
        int cc = r & 7;
        int co = r >> 3;
        int ci = cc * 4 + i;
        ws[1024 + t] = w[(ci * 64 + co) * 27 + k3];
    }
}

// grid: 16 * 31 * 16 = 7936 blocks of 256
__global__ __launch_bounds__(256) void main_kernel(const float* __restrict__ x,
                                                   const float* __restrict__ ws_ro,
                                                   float* __restrict__ accS) {
    __shared__ float tile[6144];  // [dd 2][hh 3][iw 32][ci 32], ci blocks XOR-swizzled

    int bid = blockIdx.x;
    int b   = bid / 496;
    int r   = bid - b * 496;
    int wd  = r >> 4;   // [0,31)
    int whg = r & 15;   // wh pair group
    int tid = threadIdx.x;

    // ---- stage x tile: id in {wd,wd+1}, ih in {2whg..2whg+2} (clamped), all iw, all ci
    const float* xb = x + (size_t)b * 32u * 32768u;
#pragma unroll
    for (int it = 0; it < 24; ++it) {
        int idx   = tid + it * 256;   // [0,6144)
        int iw    = idx & 31;
        int rest  = idx >> 5;         // [0,192)
        int hh    = rest % 3;
        int rest2 = rest / 3;         // [0,64)
        int dd    = rest2 & 1;
        int ci    = rest2 >> 1;
        int id    = wd + dd;
        int ih    = 2 * whg + hh; if (ih > 31) ih = 31;  // clamped row only used by masked lanes
        float v = xb[(size_t)ci * 32768u + (size_t)(id * 1024 + ih * 32 + iw)];
        int cc = ci >> 2;
        int st = ((dd * 3 + hh) * 32 + iw) * 32 + (((cc ^ (iw & 7)) << 2) | (ci & 3));
        tile[st] = v;
    }
    __syncthreads();

    int  lane = tid & 63;
    int  wave = tid >> 6;
    int  ww   = lane & 31;
    int  whl  = lane >> 5;          // 0/1 -> which wh of the pair
    int  wh   = 2 * whg + whl;
    bool act  = (ww < 31) && (wh < 31);
    int  wwc  = (ww < 31) ? ww : 30;  // clamp for in-bounds LDS addressing
    int  co_base = wave * 16;

    const float4* wT4 = (const float4*)(ws_ro + 1024);

    for (int cog = 0; cog < 2; ++cog) {
        int co8 = co_base + cog * 8;
        float acc[8][8];
#pragma unroll
        for (int j = 0; j < 8; ++j)
#pragma unroll
            for (int e = 0; e < 8; ++e) acc[j][e] = 0.f;

        for (int cc = 0; cc < 8; ++cc) {
            float4 xv[8];
#pragma unroll
            for (int dd = 0; dd < 2; ++dd)
#pragma unroll
                for (int dh = 0; dh < 2; ++dh)
#pragma unroll
                    for (int dw = 0; dw < 2; ++dw) {
                        int iw = wwc + dw;
                        int ad = ((dd * 3 + whl + dh) * 32 + iw) * 32 + ((cc ^ (iw & 7)) << 2);
                        xv[dd * 4 + dh * 2 + dw] = *(const float4*)&tile[ad];
                    }
#pragma unroll
            for (int j = 0; j < 8; ++j) {
                const float4* wp = wT4 + ((size_t)(co8 + j) * 8 + (size_t)cc) * 27;
#pragma unroll
                for (int kd = 0; kd < 3; ++kd) {
                    const int dd = (kd == 0) ? 1 : 0;
                    const int ed = (kd == 1) ? 0 : 1;
#pragma unroll
                    for (int kh = 0; kh < 3; ++kh) {
                        const int dh = (kh == 0) ? 1 : 0;
                        const int eh = (kh == 1) ? 0 : 1;
#pragma unroll
                        for (int kw = 0; kw < 3; ++kw) {
                            const int dw = (kw == 0) ? 1 : 0;
                            const int ew = (kw == 1) ? 0 : 1;
                            const float4 wv = wp[kd * 9 + kh * 3 + kw];
                            const float4 xx = xv[dd * 4 + dh * 2 + dw];
                            acc[j][ed * 4 + eh * 2 + ew] +=
                                xx.x * wv.x + xx.y * wv.y + xx.z * wv.z + xx.w * wv.w;
                        }
                    }
                }
            }
        }

        // per-window max over 8 parities -> masked 64-lane sum -> one atomic per wave/co
#pragma unroll
        for (int j = 0; j < 8; ++j) {
            float m = acc[j][0];
#pragma unroll
            for (int e = 1; e < 8; ++e) m = fmaxf(m, acc[j][e]);
            if (!act) m = 0.f;
#pragma unroll
            for (int off = 32; off > 0; off >>= 1) m += __shfl_xor(m, off, 64);
            if (lane == 0) atomicAdd(&accS[b * 64 + co8 + j], m);
        }
    }
}

__global__ __launch_bounds__(256) void finalize_kernel(const float* __restrict__ accS,
                                                       const float* __restrict__ bias,
                                                       float* __restrict__ out) {
    int i = blockIdx.x * 256 + threadIdx.x;
    if (i < 1024) {
        int co = i & 63;
        float v = (accS[i] * (1.f / (float)NWIN) + bias[co]) * 0.5f;
        v = fminf(fmaxf(v, 0.f), 1.f);
        out[i] = v;
    }
}

extern "C" void kernel_launch(void* const* d_in, const int* in_sizes, int n_in,
                              void* d_out, int out_size, void* d_ws, size_t ws_size,
                              hipStream_t stream) {
    const float* x    = (const float*)d_in[0];
    const float* w    = (const float*)d_in[1];
    const float* bias = (const float*)d_in[2];
    float* out = (float*)d_out;
    float* ws  = (float*)d_ws;

    prep_kernel<<<220, 256, 0, stream>>>(w, ws);            // zero acc + transpose w
    main_kernel<<<16 * 31 * 16, 256, 0, stream>>>(x, ws, ws);
    finalize_kernel<<<4, 256, 0, stream>>>(ws, bias, out);
}

// Round 2
// 137.683 us; speedup vs baseline: 31.4624x; 31.4624x over previous
//
#include <hip/hip_runtime.h>

// x[16,32,32,32,32] f32, w[32,64,3,3,3] f32, b[64] f32
// ConvTranspose3d(s=2,p=1,k=3) -> (+bias)*0.5 -> maxpool2 -> mean -> clamp[0,1] -> out[16,64]
//
// Window algebra (validated round 0): window w covers conv outputs {2w,2w+1}/dim,
// inputs {w,w+1}/dim; per-dim (delta,k,parity): (0,1,0) (0,2,1) (1,0,1); no bounds checks.
//
// MFMA mapping (16x16x32 bf16): M=16 windows(ww), N=16 co, K=32=Cin.
// A[m=lane&15][k=(lane>>4)*8+j] = x(window m + delta, ci=k)
// B[k=(lane>>4)*8+j][n=lane&15] = w[ci=k][co=n][tap]
// C/D: col n=lane&15, row m=(lane>>4)*4+r
//
// ws: [0,4096)B accS[16][64] f32; [4096,...) wB bf16 [tap27][cotile4][lane64][j8]

typedef __bf16 bf16x8 __attribute__((ext_vector_type(8)));
typedef float  f32x4  __attribute__((ext_vector_type(4)));
typedef unsigned short ushort_t;
typedef ushort_t ushort8 __attribute__((ext_vector_type(8)));

#define NWIN 29791  // 31^3

__device__ inline ushort_t f2bf(float f) {
    unsigned u = __builtin_bit_cast(unsigned, f);
    u += 0x7FFFu + ((u >> 16) & 1u);   // RNE
    return (ushort_t)(u >> 16);
}

__global__ __launch_bounds__(256) void prep_kernel(const float* __restrict__ w,
                                                   float* __restrict__ ws) {
    int idx = blockIdx.x * 256 + threadIdx.x;
    if (idx < 1024) ws[idx] = 0.f;
    if (idx < 55296) {
        ushort_t* wB = (ushort_t*)((char*)ws + 4096);
        int t = idx >> 11;          // tap [0,27)
        int c = (idx >> 9) & 3;     // co tile
        int l = (idx >> 3) & 63;    // lane
        int j = idx & 7;
        int ci = ((l >> 4) << 3) + j;
        int co = (c << 4) + (l & 15);
        wB[idx] = f2bf(w[(ci * 64 + co) * 27 + t]);
    }
}

// grid = 16 b * 31 wd * 8 whg
__global__ __launch_bounds__(256, 2) void main_kernel(const float* __restrict__ x,
                                                      const float* __restrict__ ws_ro,
                                                      float* __restrict__ accS) {
    __shared__ ushort_t xT[10240];  // [dd2][hh5][w32][ci32] bf16, kq XOR-swizzled by (w&3)

    int bid = blockIdx.x;
    int b   = bid / 248;
    int r   = bid - b * 248;
    int wd  = r >> 3;    // [0,31)
    int whg = r & 7;     // wh group of 4
    int tid = threadIdx.x;
    int lane = tid & 63;
    int wave = tid >> 6;

    // ---- load this wave's 27 weight B-frags into registers
    const bf16x8* wBv = (const bf16x8*)((const char*)ws_ro + 4096);
    bf16x8 Bf[27];
#pragma unroll
    for (int t = 0; t < 27; ++t) Bf[t] = wBv[(t * 4 + wave) * 64 + lane];

    // ---- stage x tile to LDS as bf16: d in {wd,wd+1}, h in [whg*4, whg*4+5), all w, all ci
    const float* xb = x + (size_t)b * (32u * 32768u);
#pragma unroll
    for (int it = 0; it < 5; ++it) {
        int c  = tid + (it << 8);       // [0,1280) b128 chunks
        int w  = c & 31;
        int kq = (c >> 5) & 3;
        int hh = (c >> 7) % 5;
        int dd = c / 640;
        int h  = (whg << 2) + hh; if (h > 31) h = 31;
        const float* src = xb + (size_t)(kq * 8) * 32768u
                              + (size_t)((((wd + dd) << 5) + h) << 5) + w;
        ushort8 pk;
#pragma unroll
        for (int i = 0; i < 8; ++i) pk[i] = f2bf(src[(size_t)i * 32768u]);
        *(ushort8*)&xT[((((dd * 5 + hh) << 5) + w) << 5) + ((kq ^ (w & 3)) << 3)] = pk;
    }
    __syncthreads();

    int m  = lane & 15;
    int kq = lane >> 4;
    float runsum = 0.f;

#pragma unroll 1
    for (int whOff = 0; whOff < 4; ++whOff) {
        int wh = (whg << 2) + whOff;
        if (wh >= 31) break;  // block-uniform
#pragma unroll 1
        for (int half = 0; half < 2; ++half) {
            int wbase = half << 4;

            // 8 A-frags (one ds_read_b128 each, conflict-free permuted-1KB pattern)
            bf16x8 Af[8];
#pragma unroll
            for (int dd = 0; dd < 2; ++dd)
#pragma unroll
                for (int dh = 0; dh < 2; ++dh)
#pragma unroll
                    for (int dw = 0; dw < 2; ++dw) {
                        int w = wbase + m + dw; if (w > 31) w = 31;
                        int ad = ((((dd * 5 + whOff + dh) << 5) + w) << 5)
                               + ((kq ^ (w & 3)) << 3);
                        Af[dd * 4 + dh * 2 + dw] = *(const bf16x8*)&xT[ad];
                    }

            f32x4 C[8];
#pragma unroll
            for (int e = 0; e < 8; ++e) C[e] = (f32x4){0.f, 0.f, 0.f, 0.f};

#pragma unroll
            for (int kd = 0; kd < 3; ++kd) {
                const int dd = (kd == 0) ? 1 : 0, ed = (kd == 1) ? 0 : 1;
#pragma unroll
                for (int kh = 0; kh < 3; ++kh) {
                    const int dh = (kh == 0) ? 1 : 0, eh = (kh == 1) ? 0 : 1;
#pragma unroll
                    for (int kw = 0; kw < 3; ++kw) {
                        const int dw = (kw == 0) ? 1 : 0, ew = (kw == 1) ? 0 : 1;
                        C[ed * 4 + eh * 2 + ew] = __builtin_amdgcn_mfma_f32_16x16x32_bf16(
                            Af[dd * 4 + dh * 2 + dw], Bf[kd * 9 + kh * 3 + kw],
                            C[ed * 4 + eh * 2 + ew], 0, 0, 0);
                    }
                }
            }

            // max over 8 parities (elementwise), then masked row-sum
            f32x4 mx = C[0];
#pragma unroll
            for (int e = 1; e < 8; ++e)
#pragma unroll
                for (int q = 0; q < 4; ++q) mx[q] = fmaxf(mx[q], C[e][q]);
#pragma unroll
            for (int rr = 0; rr < 4; ++rr) {
                int ww = wbase + (kq << 2) + rr;
                if (ww < 31) runsum += mx[rr];
            }
        }
    }

    // lanes with same n=(lane&15) hold partial sums for the same co
    runsum += __shfl_xor(runsum, 16, 64);
    runsum += __shfl_xor(runsum, 32, 64);
    if (lane < 16) atomicAdd(&accS[(b << 6) + (wave << 4) + lane], runsum);
}

__global__ __launch_bounds__(256) void finalize_kernel(const float* __restrict__ accS,
                                                       const float* __restrict__ bias,
                                                       float* __restrict__ out) {
    int i = blockIdx.x * 256 + threadIdx.x;
    if (i < 1024) {
        int co = i & 63;
        float v = (accS[i] * (1.f / (float)NWIN) + bias[co]) * 0.5f;
        v = fminf(fmaxf(v, 0.f), 1.f);
        out[i] = v;
    }
}

extern "C" void kernel_launch(void* const* d_in, const int* in_sizes, int n_in,
                              void* d_out, int out_size, void* d_ws, size_t ws_size,
                              hipStream_t stream) {
    const float* x    = (const float*)d_in[0];
    const float* w    = (const float*)d_in[1];
    const float* bias = (const float*)d_in[2];
    float* out = (float*)d_out;
    float* ws  = (float*)d_ws;

    prep_kernel<<<216, 256, 0, stream>>>(w, ws);
    main_kernel<<<16 * 31 * 8, 256, 0, stream>>>(x, ws, ws);
    finalize_kernel<<<4, 256, 0, stream>>>(ws, bias, out);
}